// Round 1
// baseline (2248.234 us; speedup 1.0000x reference)
//
#include <hip/hip_runtime.h>
#include <math.h>

#define TOK 8192   // B*S tokens
#define HD  512    // hidden
#define NE  8      // experts
#define DFF 2048   // ffn dim
#define BM  16     // tokens per ffn block
#define FC  256    // dff chunk

// ---------------- gating ----------------
__global__ __launch_bounds__(256) void gate_kernel(
    const float* __restrict__ x, const float* __restrict__ gW, const float* __restrict__ gb,
    int* __restrict__ seg_count, float* __restrict__ probs_sum,
    int* __restrict__ seg_token, float* __restrict__ seg_w)
{
    __shared__ float sW[HD * NE];   // 16 KB gate weights
    __shared__ float psum[NE];
    __shared__ int   lcount[NE];
    __shared__ int   lbase[NE];

    int tid = threadIdx.x;
    for (int i = tid; i < HD * NE; i += 256) sW[i] = gW[i];
    if (tid < NE) { psum[tid] = 0.f; lcount[tid] = 0; }
    __syncthreads();

    int t = blockIdx.x * 256 + tid;
    float logit[NE];
    #pragma unroll
    for (int e = 0; e < NE; e++) logit[e] = gb[e];

    const float4* xr4 = reinterpret_cast<const float4*>(x + (size_t)t * HD);
    for (int j4 = 0; j4 < HD / 4; j4++) {
        float4 xv = xr4[j4];
        int j = j4 * 4;
        #pragma unroll
        for (int e = 0; e < NE; e++) {
            logit[e] += xv.x * sW[(j + 0) * NE + e] + xv.y * sW[(j + 1) * NE + e]
                      + xv.z * sW[(j + 2) * NE + e] + xv.w * sW[(j + 3) * NE + e];
        }
    }

    // full softmax probs (for l_aux)
    float mx = logit[0];
    #pragma unroll
    for (int e = 1; e < NE; e++) mx = fmaxf(mx, logit[e]);
    float pe[NE]; float s = 0.f;
    #pragma unroll
    for (int e = 0; e < NE; e++) { pe[e] = expf(logit[e] - mx); s += pe[e]; }
    float inv = 1.f / s;
    #pragma unroll
    for (int e = 0; e < NE; e++) atomicAdd(&psum[e], pe[e] * inv);

    // top-2, lowest-index tie break (strict > keeps first occurrence, matches lax.top_k)
    int i0 = 0; float v0 = logit[0];
    #pragma unroll
    for (int e = 1; e < NE; e++) if (logit[e] > v0) { v0 = logit[e]; i0 = e; }
    int i1 = -1; float v1 = -3.4e38f;
    #pragma unroll
    for (int e = 0; e < NE; e++) if (e != i0 && logit[e] > v1) { v1 = logit[e]; i1 = e; }
    float e1 = expf(v1 - v0);
    float w0 = 1.f / (1.f + e1);
    float w1 = e1 / (1.f + e1);

    // block-aggregated segment append (8 global atomics per block)
    int r0 = atomicAdd(&lcount[i0], 1);
    int r1 = atomicAdd(&lcount[i1], 1);
    __syncthreads();
    if (tid < NE) lbase[tid] = atomicAdd(&seg_count[tid], lcount[tid]);
    __syncthreads();
    int p0 = lbase[i0] + r0;
    seg_token[i0 * TOK + p0] = t; seg_w[i0 * TOK + p0] = w0;
    int p1 = lbase[i1] + r1;
    seg_token[i1 * TOK + p1] = t; seg_w[i1 * TOK + p1] = w1;

    __syncthreads();
    if (tid < NE) atomicAdd(&probs_sum[tid], psum[tid]);
}

// ---------------- l_aux + counts ----------------
__global__ void finalize_kernel(const int* __restrict__ seg_count,
                                const float* __restrict__ probs_sum,
                                float* __restrict__ out_tail)
{
    int tid = threadIdx.x;
    __shared__ float p2[NE];
    if (tid < NE) {
        float p = probs_sum[tid] * (1.f / (float)TOK);
        p2[tid] = p * p;
        out_tail[1 + tid] = (float)seg_count[tid];
    }
    __syncthreads();
    if (tid == 0) {
        float ssum = 0.f;
        #pragma unroll
        for (int e = 0; e < NE; e++) ssum += p2[e];
        out_tail[0] = ssum * (float)NE;
    }
}

// ---------------- fused expert FFN ----------------
// One block = BM tokens of one expert. W1/W2 each read exactly once per block.
__global__ __launch_bounds__(256) void ffn_kernel(
    const float* __restrict__ x,
    const float* __restrict__ W1, const float* __restrict__ b1,
    const float* __restrict__ W2, const float* __restrict__ b2,
    const int* __restrict__ seg_count, const int* __restrict__ seg_token,
    const float* __restrict__ seg_w, float* __restrict__ out)
{
    int e = blockIdx.y;
    int cnt = seg_count[e];
    int n0 = blockIdx.x * BM;
    if (n0 >= cnt) return;
    int rows = min(BM, cnt - n0);

    __shared__ float xs[BM][HD];   // 32 KB
    __shared__ float hs[BM][FC];   // 16 KB
    __shared__ int   tok_s[BM];
    __shared__ float wgt_s[BM];

    int tid = threadIdx.x;
    if (tid < BM) {
        int idx = (tid < rows) ? (n0 + tid) : n0;            // pad rows point at row 0
        tok_s[tid] = seg_token[e * TOK + idx];
        wgt_s[tid] = (tid < rows) ? seg_w[e * TOK + idx] : 0.f;  // weight 0 => no contribution
    }
    __syncthreads();

    for (int m = 0; m < BM; m++) {
        const float* xrow = x + (size_t)tok_s[m] * HD;
        for (int j = tid; j < HD; j += 256) xs[m][j] = xrow[j];
    }

    int lane = tid & 63, wv = tid >> 6;
    int c0 = wv * 128 + lane;        // this thread owns output cols c0 and c0+64 for all BM tokens
    float acc0[BM], acc1[BM];
    #pragma unroll
    for (int m = 0; m < BM; m++) { acc0[m] = 0.f; acc1[m] = 0.f; }

    __syncthreads();

    for (int f0 = 0; f0 < DFF; f0 += FC) {
        // phase A: h[f0+tid] for all BM tokens (W1 column f0+tid, lane-coalesced)
        float ha[BM];
        float bv = b1[(size_t)e * DFF + f0 + tid];
        #pragma unroll
        for (int m = 0; m < BM; m++) ha[m] = bv;
        const float* w1p = W1 + (size_t)e * HD * DFF + f0 + tid;
        for (int h = 0; h < HD; h += 4) {
            float wa = w1p[(size_t)(h + 0) * DFF];
            float wb = w1p[(size_t)(h + 1) * DFF];
            float wc = w1p[(size_t)(h + 2) * DFF];
            float wd = w1p[(size_t)(h + 3) * DFF];
            #pragma unroll
            for (int m = 0; m < BM; m++) {
                float4 xv = *reinterpret_cast<const float4*>(&xs[m][h]);
                ha[m] += xv.x * wa + xv.y * wb + xv.z * wc + xv.w * wd;
            }
        }
        __syncthreads();   // previous phase B done reading hs
        #pragma unroll
        for (int m = 0; m < BM; m++) {
            float v = ha[m];
            hs[m][tid] = 0.5f * v * (1.f + erff(v * 0.70710678118654752f));  // exact gelu
        }
        __syncthreads();   // hs ready

        // phase B: rank-FC update of out tile (W2 rows f0..f0+FC, lane-coalesced)
        const float* w2p = W2 + ((size_t)e * DFF + f0) * HD;
        for (int f = 0; f < FC; f += 4) {
            float a0 = w2p[(size_t)(f + 0) * HD + c0];
            float a1 = w2p[(size_t)(f + 1) * HD + c0];
            float a2 = w2p[(size_t)(f + 2) * HD + c0];
            float a3 = w2p[(size_t)(f + 3) * HD + c0];
            float c1 = w2p[(size_t)(f + 0) * HD + c0 + 64];
            float c2 = w2p[(size_t)(f + 1) * HD + c0 + 64];
            float c3 = w2p[(size_t)(f + 2) * HD + c0 + 64];
            float c4 = w2p[(size_t)(f + 3) * HD + c0 + 64];
            #pragma unroll
            for (int m = 0; m < BM; m++) {
                float4 hv = *reinterpret_cast<const float4*>(&hs[m][f]);
                acc0[m] += hv.x * a0 + hv.y * a1 + hv.z * a2 + hv.w * a3;
                acc1[m] += hv.x * c1 + hv.y * c2 + hv.z * c3 + hv.w * c4;
            }
        }
    }

    float bias0 = b2[(size_t)e * HD + c0];
    float bias1 = b2[(size_t)e * HD + c0 + 64];
    #pragma unroll
    for (int m = 0; m < BM; m++) {
        float wgt = wgt_s[m];
        size_t ob = (size_t)tok_s[m] * HD;
        atomicAdd(&out[ob + c0],      (acc0[m] + bias0) * wgt);
        atomicAdd(&out[ob + c0 + 64], (acc1[m] + bias1) * wgt);
    }
}

extern "C" void kernel_launch(void* const* d_in, const int* in_sizes, int n_in,
                              void* d_out, int out_size, void* d_ws, size_t ws_size,
                              hipStream_t stream)
{
    const float* x  = (const float*)d_in[0];
    const float* gW = (const float*)d_in[1];
    const float* gb = (const float*)d_in[2];
    const float* W1 = (const float*)d_in[3];
    const float* b1 = (const float*)d_in[4];
    const float* W2 = (const float*)d_in[5];
    const float* b2 = (const float*)d_in[6];
    float* out = (float*)d_out;

    // workspace layout
    int*   seg_count = (int*)d_ws;                                   // 8 ints
    float* probs_sum = (float*)((char*)d_ws + 32);                   // 8 floats
    int*   seg_token = (int*)((char*)d_ws + 256);                    // [NE][TOK]
    float* seg_w     = (float*)((char*)d_ws + 256 + (size_t)NE * TOK * 4);

    // ws/out are poisoned 0xAA before every timed launch: zero what we accumulate into
    hipMemsetAsync(d_ws, 0, 64, stream);
    hipMemsetAsync(d_out, 0, (size_t)TOK * HD * sizeof(float), stream);

    gate_kernel<<<TOK / 256, 256, 0, stream>>>(x, gW, gb, seg_count, probs_sum, seg_token, seg_w);
    finalize_kernel<<<1, 64, 0, stream>>>(seg_count, probs_sum, out + (size_t)TOK * HD);
    ffn_kernel<<<dim3(TOK / BM, NE), 256, 0, stream>>>(x, W1, b1, W2, b2,
                                                       seg_count, seg_token, seg_w, out);
}

// Round 2
// 859.376 us; speedup vs baseline: 2.6161x; 2.6161x over previous
//
#include <hip/hip_runtime.h>
#include <math.h>

#define TOK 8192   // B*S tokens
#define HD  512    // hidden
#define NE  8      // experts
#define DFF 2048   // ffn dim

// ---------- bf16 helpers ----------
typedef __attribute__((ext_vector_type(8))) short bf16x8;
typedef __attribute__((ext_vector_type(4))) float floatx4;

__device__ inline unsigned short f2bf(float f) {
    union { float f; unsigned u; } v; v.f = f;
    unsigned r = v.u + 0x7FFFu + ((v.u >> 16) & 1u);   // round-nearest-even
    return (unsigned short)(r >> 16);
}

// ---------------- gating (fp32, exact) ----------------
__global__ __launch_bounds__(256) void gate_kernel(
    const float* __restrict__ x, const float* __restrict__ gW, const float* __restrict__ gb,
    int* __restrict__ seg_count, float* __restrict__ probs_sum,
    int* __restrict__ seg_token, float* __restrict__ seg_w)
{
    __shared__ float sW[HD * NE];
    __shared__ float psum[NE];
    __shared__ int   lcount[NE];
    __shared__ int   lbase[NE];

    int tid = threadIdx.x;
    for (int i = tid; i < HD * NE; i += 256) sW[i] = gW[i];
    if (tid < NE) { psum[tid] = 0.f; lcount[tid] = 0; }
    __syncthreads();

    int t = blockIdx.x * 256 + tid;
    float logit[NE];
    #pragma unroll
    for (int e = 0; e < NE; e++) logit[e] = gb[e];

    const float4* xr4 = reinterpret_cast<const float4*>(x + (size_t)t * HD);
    for (int j4 = 0; j4 < HD / 4; j4++) {
        float4 xv = xr4[j4];
        int j = j4 * 4;
        #pragma unroll
        for (int e = 0; e < NE; e++) {
            logit[e] += xv.x * sW[(j + 0) * NE + e] + xv.y * sW[(j + 1) * NE + e]
                      + xv.z * sW[(j + 2) * NE + e] + xv.w * sW[(j + 3) * NE + e];
        }
    }

    float mx = logit[0];
    #pragma unroll
    for (int e = 1; e < NE; e++) mx = fmaxf(mx, logit[e]);
    float pe[NE]; float s = 0.f;
    #pragma unroll
    for (int e = 0; e < NE; e++) { pe[e] = expf(logit[e] - mx); s += pe[e]; }
    float inv = 1.f / s;
    #pragma unroll
    for (int e = 0; e < NE; e++) atomicAdd(&psum[e], pe[e] * inv);

    // top-2, lowest-index tie break (matches jax.lax.top_k)
    int i0 = 0; float v0 = logit[0];
    #pragma unroll
    for (int e = 1; e < NE; e++) if (logit[e] > v0) { v0 = logit[e]; i0 = e; }
    int i1 = -1; float v1 = -3.4e38f;
    #pragma unroll
    for (int e = 0; e < NE; e++) if (e != i0 && logit[e] > v1) { v1 = logit[e]; i1 = e; }
    float e1 = expf(v1 - v0);
    float w0 = 1.f / (1.f + e1);
    float w1 = e1 / (1.f + e1);

    int r0 = atomicAdd(&lcount[i0], 1);
    int r1 = atomicAdd(&lcount[i1], 1);
    __syncthreads();
    if (tid < NE) lbase[tid] = atomicAdd(&seg_count[tid], lcount[tid]);
    __syncthreads();
    int p0 = lbase[i0] + r0;
    seg_token[i0 * TOK + p0] = t; seg_w[i0 * TOK + p0] = w0;
    int p1 = lbase[i1] + r1;
    seg_token[i1 * TOK + p1] = t; seg_w[i1 * TOK + p1] = w1;

    __syncthreads();
    if (tid < NE) atomicAdd(&probs_sum[tid], psum[tid]);
}

// ---------------- l_aux + counts ----------------
__global__ void finalize_kernel(const int* __restrict__ seg_count,
                                const float* __restrict__ probs_sum,
                                float* __restrict__ out_tail)
{
    int tid = threadIdx.x;
    __shared__ float p2[NE];
    if (tid < NE) {
        float p = probs_sum[tid] * (1.f / (float)TOK);
        p2[tid] = p * p;
        out_tail[1 + tid] = (float)seg_count[tid];
    }
    __syncthreads();
    if (tid == 0) {
        float ssum = 0.f;
        #pragma unroll
        for (int e = 0; e < NE; e++) ssum += p2[e];
        out_tail[0] = ssum * (float)NE;
    }
}

// ---------------- conversion kernels ----------------
__global__ __launch_bounds__(256) void convert_x_kernel(const float* __restrict__ x,
                                                        unsigned short* __restrict__ xb)
{
    int t = blockIdx.x * 256 + threadIdx.x;       // one float4 per thread
    const float4* src = (const float4*)x;
    float4 v = src[t];
    ushort4 o;
    o.x = f2bf(v.x); o.y = f2bf(v.y); o.z = f2bf(v.z); o.w = f2bf(v.w);
    ((ushort4*)xb)[t] = o;
}

// in: [E][R][C] fp32  ->  out: [E][C][R] bf16
__global__ __launch_bounds__(256) void transpose_bf16_kernel(const float* __restrict__ in,
                                                             unsigned short* __restrict__ out,
                                                             int R, int C)
{
    __shared__ float tile[32][33];
    int e = blockIdx.z;
    const float* src = in + (size_t)e * R * C;
    unsigned short* dst = out + (size_t)e * R * C;
    int c0 = blockIdx.x * 32, r0 = blockIdx.y * 32;
    int lc = threadIdx.x & 31, lr = threadIdx.x >> 5;   // lr in 0..7
    for (int rr = lr; rr < 32; rr += 8)
        tile[rr][lc] = src[(size_t)(r0 + rr) * C + c0 + lc];
    __syncthreads();
    for (int cc = lr; cc < 32; cc += 8)
        dst[(size_t)(c0 + cc) * R + r0 + lc] = f2bf(tile[lc][cc]);
}

// ---------------- fused MFMA expert FFN ----------------
#define BMT 64     // tokens per block
#define FK  64     // dff chunk
#define XS_LD 520  // xs leading dim (bf16 elems): 1040 B, 16B-aligned, banks 2-way-free
#define HS_LD 72   // hs leading dim: 144 B, 16B-aligned

__global__ __launch_bounds__(256, 2) void ffn_mfma_kernel(
    const unsigned short* __restrict__ xb,
    const unsigned short* __restrict__ W1t,   // [E][DFF][HD] bf16 (n-major)
    const float* __restrict__ b1,
    const unsigned short* __restrict__ W2t,   // [E][HD][DFF] bf16 (n-major)
    const float* __restrict__ b2,
    const int* __restrict__ seg_count, const int* __restrict__ seg_token,
    const float* __restrict__ seg_w, float* __restrict__ out)
{
    int e = blockIdx.y;
    int cnt = seg_count[e];
    int n0 = blockIdx.x * BMT;
    if (n0 >= cnt) return;
    int rows = min(BMT, cnt - n0);

    __shared__ unsigned short xs[BMT * XS_LD];   // 66560 B
    __shared__ unsigned short hs[BMT * HS_LD];   //  9216 B
    __shared__ int   tok_s[BMT];
    __shared__ float wgt_s[BMT];

    int tid = threadIdx.x;
    if (tid < BMT) {
        int idx = (tid < rows) ? (n0 + tid) : n0;            // pad rows duplicate row 0
        tok_s[tid] = seg_token[e * TOK + idx];
        wgt_s[tid] = (tid < rows) ? seg_w[e * TOK + idx] : 0.f;
    }
    __syncthreads();

    // stage x rows (bf16): 4 threads per row, 16B vectors
    {
        int r = tid >> 2, q = tid & 3;
        const uint4* src = (const uint4*)(xb + (size_t)tok_s[r] * HD) + q * 16;
        uint4* dst = (uint4*)&xs[r * XS_LD + q * 128];
        #pragma unroll
        for (int i = 0; i < 16; i++) dst[i] = src[i];
    }
    __syncthreads();

    int w  = tid >> 6;          // wave id 0..3
    int l  = tid & 63;
    int lr = l & 15;            // in-tile row/col index
    int lk = (l >> 4) * 8;      // in-tile k offset
    int crow = (l >> 4) * 4;    // C-layout row base

    const unsigned short* w1e = W1t + (size_t)e * DFF * HD;
    const unsigned short* w2e = W2t + (size_t)e * HD * DFF;

    floatx4 acc2[4][8];         // 64 M x 128 N per wave
    #pragma unroll
    for (int i = 0; i < 4; i++)
        #pragma unroll
        for (int j = 0; j < 8; j++)
            acc2[i][j] = (floatx4){0.f, 0.f, 0.f, 0.f};

    for (int fc0 = 0; fc0 < DFF; fc0 += FK) {
        // ---- GEMM1: h-chunk = xs(64x512) @ W1[:, fc0:fc0+64]; wave w does M rows 16w..16w+16
        floatx4 acc1[4];
        #pragma unroll
        for (int t = 0; t < 4; t++) acc1[t] = (floatx4){0.f, 0.f, 0.f, 0.f};

        const unsigned short* w1c = w1e + (size_t)fc0 * HD;
        for (int ks = 0; ks < HD; ks += 32) {
            bf16x8 a = *(const bf16x8*)&xs[(16 * w + lr) * XS_LD + ks + lk];
            #pragma unroll
            for (int t = 0; t < 4; t++) {
                bf16x8 b = *(const bf16x8*)(w1c + (size_t)(16 * t + lr) * HD + ks + lk);
                acc1[t] = __builtin_amdgcn_mfma_f32_16x16x32_bf16(a, b, acc1[t], 0, 0, 0);
            }
        }

        __syncthreads();   // previous GEMM2 done reading hs
        #pragma unroll
        for (int t = 0; t < 4; t++) {
            float b1v = b1[e * DFF + fc0 + 16 * t + lr];
            #pragma unroll
            for (int r = 0; r < 4; r++) {
                float v = acc1[t][r] + b1v;
                float g = 0.5f * v * (1.f + erff(v * 0.70710678118654752f));  // exact gelu
                hs[(16 * w + crow + r) * HS_LD + 16 * t + lr] = f2bf(g);
            }
        }
        __syncthreads();   // hs ready

        // ---- GEMM2: out(64x512) += h-chunk(64x64) @ W2[fc0:fc0+64, :]; wave w does N 128w..128w+128
        for (int ks = 0; ks < FK; ks += 32) {
            bf16x8 af[4];
            #pragma unroll
            for (int i = 0; i < 4; i++)
                af[i] = *(const bf16x8*)&hs[(16 * i + lr) * HS_LD + ks + lk];
            #pragma unroll
            for (int j = 0; j < 8; j++) {
                bf16x8 b = *(const bf16x8*)(w2e + (size_t)(128 * w + 16 * j + lr) * DFF + fc0 + ks + lk);
                #pragma unroll
                for (int i = 0; i < 4; i++)
                    acc2[i][j] = __builtin_amdgcn_mfma_f32_16x16x32_bf16(af[i], b, acc2[i][j], 0, 0, 0);
            }
        }
    }

    // ---- epilogue: +b2, scale by gate weight, atomic add (each out elem gets K=2 adds total)
    #pragma unroll
    for (int j = 0; j < 8; j++) {
        int n = 128 * w + 16 * j + lr;
        float b2v = b2[e * HD + n];
        #pragma unroll
        for (int i = 0; i < 4; i++) {
            #pragma unroll
            for (int r = 0; r < 4; r++) {
                int m = 16 * i + crow + r;
                float val = (acc2[i][j][r] + b2v) * wgt_s[m];
                atomicAdd(&out[(size_t)tok_s[m] * HD + n], val);
            }
        }
    }
}

// ---------------- fp32 fallback FFN (used only if ws too small) ----------------
#define BM  16
#define FC  256
__global__ __launch_bounds__(256) void ffn_kernel(
    const float* __restrict__ x,
    const float* __restrict__ W1, const float* __restrict__ b1,
    const float* __restrict__ W2, const float* __restrict__ b2,
    const int* __restrict__ seg_count, const int* __restrict__ seg_token,
    const float* __restrict__ seg_w, float* __restrict__ out)
{
    int e = blockIdx.y;
    int cnt = seg_count[e];
    int n0 = blockIdx.x * BM;
    if (n0 >= cnt) return;
    int rows = min(BM, cnt - n0);

    __shared__ float xs[BM][HD];
    __shared__ float hsl[BM][FC];
    __shared__ int   tok_s[BM];
    __shared__ float wgt_s[BM];

    int tid = threadIdx.x;
    if (tid < BM) {
        int idx = (tid < rows) ? (n0 + tid) : n0;
        tok_s[tid] = seg_token[e * TOK + idx];
        wgt_s[tid] = (tid < rows) ? seg_w[e * TOK + idx] : 0.f;
    }
    __syncthreads();

    for (int m = 0; m < BM; m++) {
        const float* xrow = x + (size_t)tok_s[m] * HD;
        for (int j = tid; j < HD; j += 256) xs[m][j] = xrow[j];
    }

    int lane = tid & 63, wv = tid >> 6;
    int c0 = wv * 128 + lane;
    float acc0[BM], acc1[BM];
    #pragma unroll
    for (int m = 0; m < BM; m++) { acc0[m] = 0.f; acc1[m] = 0.f; }
    __syncthreads();

    for (int f0 = 0; f0 < DFF; f0 += FC) {
        float ha[BM];
        float bv = b1[(size_t)e * DFF + f0 + tid];
        #pragma unroll
        for (int m = 0; m < BM; m++) ha[m] = bv;
        const float* w1p = W1 + (size_t)e * HD * DFF + f0 + tid;
        for (int h = 0; h < HD; h += 4) {
            float wa = w1p[(size_t)(h + 0) * DFF];
            float wb = w1p[(size_t)(h + 1) * DFF];
            float wc = w1p[(size_t)(h + 2) * DFF];
            float wd = w1p[(size_t)(h + 3) * DFF];
            #pragma unroll
            for (int m = 0; m < BM; m++) {
                float4 xv = *reinterpret_cast<const float4*>(&xs[m][h]);
                ha[m] += xv.x * wa + xv.y * wb + xv.z * wc + xv.w * wd;
            }
        }
        __syncthreads();
        #pragma unroll
        for (int m = 0; m < BM; m++) {
            float v = ha[m];
            hsl[m][tid] = 0.5f * v * (1.f + erff(v * 0.70710678118654752f));
        }
        __syncthreads();
        const float* w2p = W2 + ((size_t)e * DFF + f0) * HD;
        for (int f = 0; f < FC; f += 4) {
            float a0 = w2p[(size_t)(f + 0) * HD + c0];
            float a1 = w2p[(size_t)(f + 1) * HD + c0];
            float a2 = w2p[(size_t)(f + 2) * HD + c0];
            float a3 = w2p[(size_t)(f + 3) * HD + c0];
            float c1 = w2p[(size_t)(f + 0) * HD + c0 + 64];
            float c2 = w2p[(size_t)(f + 1) * HD + c0 + 64];
            float c3 = w2p[(size_t)(f + 2) * HD + c0 + 64];
            float c4 = w2p[(size_t)(f + 3) * HD + c0 + 64];
            #pragma unroll
            for (int m = 0; m < BM; m++) {
                float4 hv = *reinterpret_cast<const float4*>(&hsl[m][f]);
                acc0[m] += hv.x * a0 + hv.y * a1 + hv.z * a2 + hv.w * a3;
                acc1[m] += hv.x * c1 + hv.y * c2 + hv.z * c3 + hv.w * c4;
            }
        }
    }

    float bias0 = b2[(size_t)e * HD + c0];
    float bias1 = b2[(size_t)e * HD + c0 + 64];
    #pragma unroll
    for (int m = 0; m < BM; m++) {
        float wgt = wgt_s[m];
        size_t ob = (size_t)tok_s[m] * HD;
        atomicAdd(&out[ob + c0],      (acc0[m] + bias0) * wgt);
        atomicAdd(&out[ob + c0 + 64], (acc1[m] + bias1) * wgt);
    }
}

extern "C" void kernel_launch(void* const* d_in, const int* in_sizes, int n_in,
                              void* d_out, int out_size, void* d_ws, size_t ws_size,
                              hipStream_t stream)
{
    const float* x  = (const float*)d_in[0];
    const float* gW = (const float*)d_in[1];
    const float* gb = (const float*)d_in[2];
    const float* W1 = (const float*)d_in[3];
    const float* b1 = (const float*)d_in[4];
    const float* W2 = (const float*)d_in[5];
    const float* b2 = (const float*)d_in[6];
    float* out = (float*)d_out;

    // workspace layout
    int*   seg_count = (int*)d_ws;                                   // 8 ints @0
    float* probs_sum = (float*)((char*)d_ws + 32);                   // 8 floats
    int*   seg_token = (int*)((char*)d_ws + 256);                    // [NE][TOK]
    float* seg_w     = (float*)((char*)d_ws + 256 + (size_t)NE * TOK * 4);
    unsigned short* xb  = (unsigned short*)((char*)d_ws + (1u << 20));    // 8 MB
    unsigned short* W1t = (unsigned short*)((char*)d_ws + (16u << 20));   // 16 MB
    unsigned short* W2t = (unsigned short*)((char*)d_ws + (32u << 20));   // 16 MB
    const size_t WS_NEEDED = (size_t)48 << 20;

    hipMemsetAsync(d_ws, 0, 64, stream);
    hipMemsetAsync(d_out, 0, (size_t)TOK * HD * sizeof(float), stream);

    gate_kernel<<<TOK / 256, 256, 0, stream>>>(x, gW, gb, seg_count, probs_sum, seg_token, seg_w);
    finalize_kernel<<<1, 64, 0, stream>>>(seg_count, probs_sum, out + (size_t)TOK * HD);

    if (ws_size >= WS_NEEDED) {
        convert_x_kernel<<<TOK * HD / 4 / 256, 256, 0, stream>>>(x, xb);
        // W1 [E][HD][DFF] -> W1t [E][DFF][HD]
        transpose_bf16_kernel<<<dim3(DFF / 32, HD / 32, NE), 256, 0, stream>>>(W1, W1t, HD, DFF);
        // W2 [E][DFF][HD] -> W2t [E][HD][DFF]
        transpose_bf16_kernel<<<dim3(HD / 32, DFF / 32, NE), 256, 0, stream>>>(W2, W2t, DFF, HD);
        ffn_mfma_kernel<<<dim3(TOK / BMT, NE), 256, 0, stream>>>(
            xb, W1t, b1, W2t, b2, seg_count, seg_token, seg_w, out);
    } else {
        ffn_kernel<<<dim3(TOK / BM, NE), 256, 0, stream>>>(
            x, W1, b1, W2, b2, seg_count, seg_token, seg_w, out);
    }
}